// Round 1
// baseline (51.152 us; speedup 1.0000x reference)
//
#include <hip/hip_runtime.h>

// ---------------- problem constants ----------------
#define NC    2
#define NB    9
#define NNODE 820
#define NL    3
#define NK    17

#define SQRT2F   1.41421356237309515f
#define ISQ2PIF  0.3989422804014327f    // 1/sqrt(2*pi)
#define I2PIF    0.15915494309189535f   // 1/(2*pi)
#define EPSF     1e-30f

// output layout (flat f32 offsets, concatenated in reference return order)
#define OFF_XN    0LL
#define OFF_XE    752760LL
#define OFF_LPN   26315388LL
#define OFF_LPE   27068148LL
#define OFF_ALPHA 39849462LL
#define OFF_O1    39849516LL
#define OFF_O2    39893742LL

__device__ __forceinline__ float sel3(float a0, float a1, float a2, int i) {
    float r = a0;
    r = (i == 1) ? a1 : r;
    r = (i == 2) ? a2 : r;
    return r;
}

// ---------------- Gauss-Hermite nodes (n=17), NR gauher Newton in fp64 ----------------
__global__ void hermite_nodes_kernel(float* __restrict__ nd) {
    if (threadIdx.x != 0 || blockIdx.x != 0) return;
    const int n = 17;
    const double PIM4 = 0.7511255444649425;  // pi^{-1/4}
    double xr[9];
    double z = 0.0;
#pragma unroll
    for (int i = 0; i < 9; ++i) {
        if (i == 0)      z = sqrt((double)(2 * n + 1)) - 1.85575 * pow((double)(2 * n + 1), -0.16667);
        else if (i == 1) z -= 1.14 * pow((double)n, 0.426) / z;
        else if (i == 2) z = 1.86 * z - 0.86 * xr[0];
        else if (i == 3) z = 1.91 * z - 0.91 * xr[1];
        else             z = 2.0 * z - xr[i - 2];
        for (int it = 0; it < 14; ++it) {
            double p1 = PIM4, p2 = 0.0;
#pragma unroll
            for (int j = 1; j <= n; ++j) {
                double p3 = p2;
                p2 = p1;
                p1 = z * sqrt(2.0 / j) * p2 - sqrt((j - 1.0) / j) * p3;
            }
            double pp = sqrt(2.0 * n) * p2;
            double z1 = z;
            z = z1 - p1 / pp;
            if (fabs(z - z1) <= 3.0e-14) break;
        }
        xr[i] = z;  // descending positive roots, xr[8] ~ 0
    }
#pragma unroll
    for (int i = 0; i < 9; ++i) {
        nd[16 - i] = (float)xr[i];   // ascending order like numpy hermgauss
        nd[i]      = (float)(-xr[i]);
    }
}

// ---------------- xn + lpn over (C,BS1,820) ----------------
__global__ __launch_bounds__(64) void kernelB(const float* __restrict__ mu,
                                              const float* __restrict__ sigma,
                                              const float* __restrict__ w,
                                              const float* __restrict__ nd,
                                              float* __restrict__ out) {
    int bid = blockIdx.x;            // 0..14759 == (cb*820 + n)
    int tid = threadIdx.x;
    int cb  = bid / NNODE;           // 0..17
    int n   = bid - cb * NNODE;
    int b   = cb % NB;

    __shared__ float snd[NK];
    if (tid < NK) snd[tid] = nd[tid];

    const float* muN = mu    + (size_t)bid * 3;
    const float* sgN = sigma + (size_t)bid * 3;
    const float* wB  = w + cb * 3;

    float u0 = muN[0], u1 = muN[1], u2 = muN[2];
    float s0 = sgN[0], s1 = sgN[1], s2 = sgN[2];

    float w0 = wB[0], w1 = wB[1], w2 = wB[2];
    float wm = fmaxf(w0, fmaxf(w1, w2));
    float e0 = __expf(w0 - wm), e1 = __expf(w1 - wm), e2 = __expf(w2 - wm);
    float inv = 1.0f / (e0 + e1 + e2);
    float a0 = e0 * inv, a1 = e1 * inv, a2 = e2 * inv;

    float i0 = 1.0f / s0, i1 = 1.0f / s1, i2 = 1.0f / s2;
    float c0 = a0 * i0 * ISQ2PIF, c1 = a1 * i1 * ISQ2PIF, c2 = a2 * i2 * ISQ2PIF;

    __syncthreads();
    if (tid >= NL * NK) return;      // 51 active
    int l1 = tid / NK;
    int k  = tid - l1 * NK;

    float sl = sel3(s0, s1, s2, l1);
    float ul = sel3(u0, u1, u2, l1);
    float xn = fmaf(snd[k] * sl, SQRT2F, ul);
    out[OFF_XN + (size_t)bid * 51 + tid] = xn;

    float lp;
    if (b >= 1 && n < 729) {
        lp = 0.0f;
    } else {
        float d0 = (xn - u0) * i0;
        float d1 = (xn - u1) * i1;
        float d2 = (xn - u2) * i2;
        float sum = c0 * __expf(-0.5f * d0 * d0)
                  + c1 * __expf(-0.5f * d1 * d1)
                  + c2 * __expf(-0.5f * d2 * d2);
        lp = __logf(sum + EPSF);
    }
    out[OFF_LPN + (size_t)bid * 51 + tid] = lp;
}

// ---------------- xe + lpe + o1 + o2 over (C,BS1,819) ----------------
__global__ __launch_bounds__(128) void kernelC(const float* __restrict__ mu,
                                               const float* __restrict__ sigma,
                                               const float* __restrict__ w,
                                               const float* __restrict__ nd,
                                               float* __restrict__ out) {
    int bid = blockIdx.x;            // 0..14741 == (cb*819 + n)
    int tid = threadIdx.x;
    int cb  = bid / 819;
    int n   = bid - cb * 819;
    int b   = cb % NB;

    // closed-form _ID gather
    int id;
    if (n < 729)      { int a = n / 81;  int r = n % 27; id = 729 + a * 9 + r / 3; }
    else if (n < 810) { int m = n - 729; int a = m / 27; int r = m % 9; id = 810 + a * 3 + r / 3; }
    else              { id = 819; }

    __shared__ float snd[NK];
    if (tid < NK) snd[tid] = nd[tid];

    const float* muN = mu    + ((size_t)cb * NNODE + n) * 3;
    const float* sgN = sigma + ((size_t)cb * NNODE + n) * 3;
    const float* muI = mu    + ((size_t)cb * NNODE + id) * 3;
    const float* sgI = sigma + ((size_t)cb * NNODE + id) * 3;
    const float* wB  = w + cb * 3;

    float u1a = muN[0], u1b = muN[1], u1c = muN[2];
    float s1a = sgN[0], s1b = sgN[1], s1c = sgN[2];
    float u2a = muI[0], u2b = muI[1], u2c = muI[2];
    float s2a = sgI[0], s2b = sgI[1], s2c = sgI[2];

    float w0 = wB[0], w1 = wB[1], w2 = wB[2];
    float wm = fmaxf(w0, fmaxf(w1, w2));
    float e0 = __expf(w0 - wm), e1 = __expf(w1 - wm), e2 = __expf(w2 - wm);
    float inv = 1.0f / (e0 + e1 + e2);
    float a0 = e0 * inv, a1 = e1 * inv, a2 = e2 * inv;

    float i1a = 1.0f / s1a, i1b = 1.0f / s1b, i1c = 1.0f / s1c;
    float i2a = 1.0f / s2a, i2b = 1.0f / s2b, i2c = 1.0f / s2c;

    bool masked = (b >= 1) && (n < 729);   // b1 -> ones there
    float ca, cbv, cc;
    if (masked) {
        ca  = a0 * i2a * ISQ2PIF;
        cbv = a1 * i2b * ISQ2PIF;
        cc  = a2 * i2c * ISQ2PIF;
    } else {
        ca  = a0 * i1a * i2a * I2PIF;
        cbv = a1 * i1b * i2b * I2PIF;
        cc  = a2 * i1c * i2c * I2PIF;
    }

    if (tid < 3)      out[OFF_O1 + (size_t)bid * 3 + tid]       = sel3(s1a, s1b, s1c, tid);
    else if (tid < 6) out[OFF_O2 + (size_t)bid * 3 + (tid - 3)] = sel3(s2a, s2b, s2c, tid - 3);

    __syncthreads();

    float2* xe  = reinterpret_cast<float2*>(out + OFF_XE) + (size_t)bid * 867;
    float*  lpe = out + OFF_LPE + (size_t)bid * 867;

    for (int e = tid; e < 867; e += 128) {
        int l1 = e / 289;
        int q  = e - l1 * 289;
        int qj = q / NK;
        int qi = q - qj * NK;
        float xiv = snd[qi];
        float xjv = snd[qj];

        float s1l = sel3(s1a, s1b, s1c, l1);
        float u1l = sel3(u1a, u1b, u1c, l1);
        float s2l = sel3(s2a, s2b, s2c, l1);
        float u2l = sel3(u2a, u2b, u2c, l1);

        float x1 = fmaf(xiv * s1l, SQRT2F, u1l);
        float x2 = fmaf(xjv * s2l, SQRT2F, u2l);
        xe[e] = make_float2(x1, x2);

        float t0 = (x2 - u2a) * i2a; t0 *= t0;
        float t1 = (x2 - u2b) * i2b; t1 *= t1;
        float t2 = (x2 - u2c) * i2c; t2 *= t2;
        if (!masked) {
            float d0 = (x1 - u1a) * i1a; t0 = fmaf(d0, d0, t0);
            float d1 = (x1 - u1b) * i1b; t1 = fmaf(d1, d1, t1);
            float d2 = (x1 - u1c) * i1c; t2 = fmaf(d2, d2, t2);
        }
        float sum = ca  * __expf(-0.5f * t0)
                  + cbv * __expf(-0.5f * t1)
                  + cc  * __expf(-0.5f * t2);
        lpe[e] = __logf(sum + EPSF);
    }
}

// ---------------- alpha softmax ----------------
__global__ __launch_bounds__(64) void kernelD(const float* __restrict__ w,
                                              float* __restrict__ out) {
    int t = threadIdx.x;
    if (t >= NC * NB * NL) return;   // 54
    int cb = t / 3;
    int l  = t - cb * 3;
    const float* wB = w + cb * 3;
    float w0 = wB[0], w1 = wB[1], w2 = wB[2];
    float wm = fmaxf(w0, fmaxf(w1, w2));
    float e0 = __expf(w0 - wm), e1 = __expf(w1 - wm), e2 = __expf(w2 - wm);
    float inv = 1.0f / (e0 + e1 + e2);
    float el = (l == 0) ? e0 : ((l == 1) ? e1 : e2);
    out[OFF_ALPHA + t] = el * inv;
}

extern "C" void kernel_launch(void* const* d_in, const int* in_sizes, int n_in,
                              void* d_out, int out_size, void* d_ws, size_t ws_size,
                              hipStream_t stream) {
    const float* mu    = (const float*)d_in[0];
    const float* sigma = (const float*)d_in[1];
    const float* w     = (const float*)d_in[2];
    float* out = (float*)d_out;

    // nodes scratch: d_ws if available, else temporarily borrow the alpha slot
    // (overwritten by kernelD afterwards — stream order guarantees correctness)
    float* nd = (ws_size >= 17 * sizeof(float)) ? (float*)d_ws : (out + OFF_ALPHA);

    hipLaunchKernelGGL(hermite_nodes_kernel, dim3(1), dim3(64), 0, stream, nd);
    hipLaunchKernelGGL(kernelB, dim3(NC * NB * NNODE), dim3(64), 0, stream, mu, sigma, w, nd, out);
    hipLaunchKernelGGL(kernelC, dim3(NC * NB * 819), dim3(128), 0, stream, mu, sigma, w, nd, out);
    hipLaunchKernelGGL(kernelD, dim3(1), dim3(64), 0, stream, w, out);
}

// Round 2
// 50.614 us; speedup vs baseline: 1.0106x; 1.0106x over previous
//
#include <hip/hip_runtime.h>

// ---------------- problem constants ----------------
#define NC    2
#define NB    9
#define NNODE 820
#define NL    3
#define NK    17

#define SQRT2F   1.41421356237309515f
#define ISQ2PIF  0.3989422804014327f    // 1/sqrt(2*pi)
#define I2PIF    0.15915494309189535f   // 1/(2*pi)
#define EPSF     1e-30f

// output layout (flat f32 offsets, concatenated in reference return order)
#define OFF_XN    0LL
#define OFF_XE    752760LL
#define OFF_LPN   26315388LL
#define OFF_LPE   27068148LL
#define OFF_ALPHA 39849462LL
#define OFF_O1    39849516LL
#define OFF_O2    39893742LL

__device__ __forceinline__ float sel3(float a0, float a1, float a2, int i) {
    float r = a0;
    r = (i == 1) ? a1 : r;
    r = (i == 2) ? a2 : r;
    return r;
}

// ---------------- Gauss-Hermite nodes (n=17) ----------------
// NR gauher Newton in fp64, but with the sqrt recurrence coefficients
// precomputed in parallel into LDS (they were 2 dependent fp64 sqrts per
// recurrence step = ~25us serial; now the chain is one fp64 fma per step).
__global__ void hermite_nodes_kernel(float* __restrict__ nd) {
    __shared__ double c1[NK + 1], c2[NK + 1];
    int t = threadIdx.x;
    if (t >= 1 && t <= NK) {
        c1[t] = sqrt(2.0 / (double)t);
        c2[t] = sqrt(((double)t - 1.0) / (double)t);
    }
    __syncthreads();
    if (t != 0 || blockIdx.x != 0) return;

    const int n = NK;
    const double PIM4 = 0.7511255444649425;  // pi^{-1/4}
    const double PPC  = sqrt(2.0 * (double)n);
    double xr[9];
    double z = 0.0;
    for (int i = 0; i < 9; ++i) {
        if (i == 0)      z = sqrt((double)(2 * n + 1)) - 1.85575 * pow((double)(2 * n + 1), -0.16667);
        else if (i == 1) z -= 1.14 * pow((double)n, 0.426) / z;
        else if (i == 2) z = 1.86 * z - 0.86 * xr[0];
        else if (i == 3) z = 1.91 * z - 0.91 * xr[1];
        else             z = 2.0 * z - xr[i - 2];
        for (int it = 0; it < 14; ++it) {
            double zc[NK + 1];
#pragma unroll
            for (int j = 1; j <= n; ++j) zc[j] = z * c1[j];   // off-chain
            double p1 = PIM4, p2 = 0.0;
#pragma unroll
            for (int j = 1; j <= n; ++j) {
                double p3 = p2;
                p2 = p1;
                p1 = fma(zc[j], p2, -(c2[j] * p3));
            }
            double pp = PPC * p2;
            double z1 = z;
            z = z1 - p1 / pp;
            if (fabs(z - z1) <= 3.0e-14) break;
        }
        xr[i] = z;  // descending positive roots, xr[8] ~ 0
    }
#pragma unroll
    for (int i = 0; i < 9; ++i) {
        nd[16 - i] = (float)xr[i];   // ascending like numpy hermgauss
        nd[i]      = (float)(-xr[i]);
    }
}

// ---------------- fused main kernel: xn, lpn, xe, lpe, o1, o2, alpha ----------------
// grid = NC*NB*820 blocks; block (cb, n). Blocks with n < 819 also do the
// edge (xe/lpe/o1/o2) work for pair index (cb, n). Block 0 writes alpha.
__global__ __launch_bounds__(256) void fused_kernel(const float* __restrict__ mu,
                                                    const float* __restrict__ sigma,
                                                    const float* __restrict__ w,
                                                    const float* __restrict__ nd,
                                                    float* __restrict__ out) {
    int bid = blockIdx.x;            // cb*820 + n
    int tid = threadIdx.x;
    int cb  = bid / NNODE;           // 0..17
    int n   = bid - cb * NNODE;      // 0..819
    int b   = cb % NB;

    __shared__ float snd[NK];
    if (tid < NK) snd[tid] = nd[tid];

    const float* muN = mu    + (size_t)bid * 3;
    const float* sgN = sigma + (size_t)bid * 3;
    const float* wB  = w + cb * 3;

    float u1a = muN[0], u1b = muN[1], u1c = muN[2];
    float s1a = sgN[0], s1b = sgN[1], s1c = sgN[2];

    float w0 = wB[0], w1 = wB[1], w2 = wB[2];
    float wm = fmaxf(w0, fmaxf(w1, w2));
    float e0 = __expf(w0 - wm), e1 = __expf(w1 - wm), e2 = __expf(w2 - wm);
    float inv = 1.0f / (e0 + e1 + e2);
    float a0 = e0 * inv, a1 = e1 * inv, a2 = e2 * inv;

    float i1a = 1.0f / s1a, i1b = 1.0f / s1b, i1c = 1.0f / s1c;

    bool masked = (b >= 1) && (n < 729);

    __syncthreads();

    // ---- xn + lpn (threads 0..50) ----
    if (tid < NL * NK) {
        int l1 = tid / NK;
        int k  = tid - l1 * NK;
        float sl = sel3(s1a, s1b, s1c, l1);
        float ul = sel3(u1a, u1b, u1c, l1);
        float xn = fmaf(snd[k] * sl, SQRT2F, ul);
        out[OFF_XN + (size_t)bid * 51 + tid] = xn;

        float lp;
        if (masked) {
            lp = 0.0f;
        } else {
            float d0 = (xn - u1a) * i1a;
            float d1 = (xn - u1b) * i1b;
            float d2 = (xn - u1c) * i1c;
            float sum = (a0 * i1a) * __expf(-0.5f * d0 * d0)
                      + (a1 * i1b) * __expf(-0.5f * d1 * d1)
                      + (a2 * i1c) * __expf(-0.5f * d2 * d2);
            lp = __logf(sum * ISQ2PIF + EPSF);
        }
        out[OFF_LPN + (size_t)bid * 51 + tid] = lp;
    }

    // ---- alpha (block 0, threads 192..245) ----
    if (bid == 0 && tid >= 192 && tid < 192 + NC * NB * NL) {
        int t  = tid - 192;
        int cb2 = t / 3;
        int l   = t - cb2 * 3;
        const float* wB2 = w + cb2 * 3;
        float v0 = wB2[0], v1 = wB2[1], v2 = wB2[2];
        float vm = fmaxf(v0, fmaxf(v1, v2));
        float f0 = __expf(v0 - vm), f1 = __expf(v1 - vm), f2 = __expf(v2 - vm);
        float finv = 1.0f / (f0 + f1 + f2);
        float fl = (l == 0) ? f0 : ((l == 1) ? f1 : f2);
        out[OFF_ALPHA + t] = fl * finv;
    }

    if (n >= 819) return;            // edge work only for n < 819

    // closed-form _ID gather
    int id;
    if (n < 729)      { int a = n / 81;  int r = n % 27; id = 729 + a * 9 + r / 3; }
    else if (n < 810) { int m = n - 729; int a = m / 27; int r = m % 9; id = 810 + a * 3 + r / 3; }
    else              { id = 819; }

    const float* muI = mu    + ((size_t)cb * NNODE + id) * 3;
    const float* sgI = sigma + ((size_t)cb * NNODE + id) * 3;
    float u2a = muI[0], u2b = muI[1], u2c = muI[2];
    float s2a = sgI[0], s2b = sgI[1], s2c = sgI[2];
    float i2a = 1.0f / s2a, i2b = 1.0f / s2b, i2c = 1.0f / s2c;

    float ca, cbv, cc;
    if (masked) {       // b1 -> ones
        ca  = a0 * i2a * ISQ2PIF;
        cbv = a1 * i2b * ISQ2PIF;
        cc  = a2 * i2c * ISQ2PIF;
    } else {
        ca  = a0 * i1a * i2a * I2PIF;
        cbv = a1 * i1b * i2b * I2PIF;
        cc  = a2 * i1c * i2c * I2PIF;
    }

    size_t bid2 = (size_t)cb * 819 + n;

    if (tid >= 64 && tid < 67)       out[OFF_O1 + bid2 * 3 + (tid - 64)] = sel3(s1a, s1b, s1c, tid - 64);
    else if (tid >= 67 && tid < 70)  out[OFF_O2 + bid2 * 3 + (tid - 67)] = sel3(s2a, s2b, s2c, tid - 67);

    float2* xe  = reinterpret_cast<float2*>(out + OFF_XE) + bid2 * 867;
    float*  lpe = out + OFF_LPE + bid2 * 867;

    for (int e = tid; e < 867; e += 256) {
        int l1 = e / 289;
        int q  = e - l1 * 289;
        int qj = q / NK;
        int qi = q - qj * NK;
        float xiv = snd[qi];
        float xjv = snd[qj];

        float s1l = sel3(s1a, s1b, s1c, l1);
        float u1l = sel3(u1a, u1b, u1c, l1);
        float s2l = sel3(s2a, s2b, s2c, l1);
        float u2l = sel3(u2a, u2b, u2c, l1);

        float x1 = fmaf(xiv * s1l, SQRT2F, u1l);
        float x2 = fmaf(xjv * s2l, SQRT2F, u2l);
        xe[e] = make_float2(x1, x2);

        float t0 = (x2 - u2a) * i2a; t0 *= t0;
        float t1 = (x2 - u2b) * i2b; t1 *= t1;
        float t2 = (x2 - u2c) * i2c; t2 *= t2;
        if (!masked) {
            float d0 = (x1 - u1a) * i1a; t0 = fmaf(d0, d0, t0);
            float d1 = (x1 - u1b) * i1b; t1 = fmaf(d1, d1, t1);
            float d2 = (x1 - u1c) * i1c; t2 = fmaf(d2, d2, t2);
        }
        float sum = ca  * __expf(-0.5f * t0)
                  + cbv * __expf(-0.5f * t1)
                  + cc  * __expf(-0.5f * t2);
        lpe[e] = __logf(sum + EPSF);
    }
}

extern "C" void kernel_launch(void* const* d_in, const int* in_sizes, int n_in,
                              void* d_out, int out_size, void* d_ws, size_t ws_size,
                              hipStream_t stream) {
    const float* mu    = (const float*)d_in[0];
    const float* sigma = (const float*)d_in[1];
    const float* w     = (const float*)d_in[2];
    float* out = (float*)d_out;

    float* nd = (ws_size >= NK * sizeof(float)) ? (float*)d_ws : (out + OFF_ALPHA);

    hipLaunchKernelGGL(hermite_nodes_kernel, dim3(1), dim3(64), 0, stream, nd);
    hipLaunchKernelGGL(fused_kernel, dim3(NC * NB * NNODE), dim3(256), 0, stream,
                       mu, sigma, w, nd, out);
}